// Round 3
// baseline (152.754 us; speedup 1.0000x reference)
//
#include <hip/hip_runtime.h>
#include <math.h>

#define NBINS 1024
#define FXSCALE 1024.0f          // fixed-point scale: fx = round(v * 1024)
#define BATCH 16
#define NPER (1u << 20)          // elements per sample
#define TOPK 65536u              // NPER / 16
#define BPS 128                  // blocks per sample -> 2048 blocks = 8/CU
#define THREADS 256
// per block: NPER/BPS = 8192 elems = 2048 float4 = 8 iters/thread

#define PACK1 (1ULL << 40)       // count increment in packed (count<<40 | fxsum)
#define MASK40 ((1ULL << 40) - 1)
// overflow check: per sample-bin count <= 2^20 (fits 24b), fx-sum <= 2^20 * 7000 < 2^40. OK.

// workspace: u64 hist [BATCH][NBINS] = 131072 B
#define WS_ZERO_BYTES (BATCH * NBINS * 8)

__device__ __forceinline__ unsigned int fx_of(float x, float lab) {
    float ax = fabsf(x);
    float sp = __logf(1.0f + __expf(-ax));            // softplus(-|x|), HW exp2/log2
    bool mis = (x >= 0.0f) != (lab >= 0.5f);          // label-sign mismatch adds |x|
    float v = sp + (mis ? ax : 0.0f);                 // xentropy >= 0
    return __float2uint_rn(v * FXSCALE);              // negative -> clamps to 0
}

__global__ void __launch_bounds__(THREADS)
histsum_kernel(const float* __restrict__ outp, const float* __restrict__ labp,
               unsigned long long* __restrict__ ghist) {
    __shared__ unsigned long long lh[NBINS];          // 8 KB
    const int s = blockIdx.y;
    const int chunk = blockIdx.x;
    for (int i = threadIdx.x; i < NBINS; i += THREADS) lh[i] = 0ULL;
    __syncthreads();

    const float4* o4 = (const float4*)outp;
    const float4* l4 = (const float4*)labp;
    const size_t base4 = (size_t)s * (NPER / 4) + (size_t)chunk * (NPER / 4 / BPS);
#pragma unroll
    for (int j = 0; j < 8; ++j) {
        size_t idx = base4 + (size_t)j * THREADS + threadIdx.x;
        float4 xo = o4[idx];
        float4 xl = l4[idx];
        unsigned int fx[4] = {fx_of(xo.x, xl.x), fx_of(xo.y, xl.y),
                              fx_of(xo.z, xl.z), fx_of(xo.w, xl.w)};
#pragma unroll
        for (int q = 0; q < 4; ++q) {
            unsigned int b = fx[q] >> 4;              // bin width = 16 fx units = 1/64
            b = b > NBINS - 1 ? NBINS - 1 : b;
            atomicAdd(&lh[b], PACK1 | (unsigned long long)fx[q]);
        }
    }
    __syncthreads();

    unsigned long long* gh = ghist + (size_t)s * NBINS;
    for (int i = threadIdx.x; i < NBINS; i += THREADS) {
        unsigned long long p = lh[i];
        if (p) atomicAdd(&gh[i], p);                  // ~400 occupied bins/block
    }
}

__global__ void __launch_bounds__(THREADS)
select_final_kernel(const unsigned long long* __restrict__ ghist,
                    float* __restrict__ out) {
    const int s = blockIdx.x;
    const unsigned long long* h = ghist + (size_t)s * NBINS;
    const int t = threadIdx.x;                        // 4 consecutive bins per thread

    unsigned long long p[4];
    unsigned int cc[4];
#pragma unroll
    for (int i = 0; i < 4; ++i) { p[i] = h[t * 4 + i]; cc[i] = (unsigned int)(p[i] >> 40); }

    __shared__ unsigned int S[THREADS];
    S[t] = cc[0] + cc[1] + cc[2] + cc[3];
    __syncthreads();

    // inclusive suffix scan: S[t] = count of elements in bin-groups >= t
    for (int off = 1; off < THREADS; off <<= 1) {
        unsigned int v = (t + off < THREADS) ? S[t + off] : 0u;
        __syncthreads();
        S[t] += v;
        __syncthreads();
    }

    __shared__ int sh_bst;
    __shared__ unsigned int sh_cabove;
    unsigned int above_group = (t + 1 < THREADS) ? S[t + 1] : 0u;
    if (S[t] >= TOPK && above_group < TOPK) {         // unique winner group
        unsigned int cum = above_group;
        int bs = t * 4;
        for (int i = 3; i >= 0; --i) {
            if (cum + cc[i] >= TOPK) { bs = t * 4 + i; break; }
            cum += cc[i];
        }
        sh_bst = bs; sh_cabove = cum;
    }
    __syncthreads();
    const int bst = sh_bst;
    const unsigned int cabove = sh_cabove;

    // exact sum of quantized values in bins strictly above bst
    double local = 0.0;
#pragma unroll
    for (int i = 0; i < 4; ++i) {
        int b = t * 4 + i;
        if (b > bst) local += (double)(p[i] & MASK40);
    }
    __shared__ double R[THREADS];
    R[t] = local;
    __syncthreads();
    for (int off = THREADS / 2; off > 0; off >>= 1) {
        if (t < off) R[t] += R[t + off];
        __syncthreads();
    }
    if (t == 0) {
        unsigned long long pb = h[bst];
        unsigned int cb = (unsigned int)(pb >> 40);
        double sumAbove = R[0] / (double)FXSCALE;
        double avg = cb ? ((double)(pb & MASK40) / (double)FXSCALE) / (double)cb : 0.0;
        double needed = (double)(TOPK - cabove);
        double mean = (sumAbove + needed * avg) / (double)TOPK;
        atomicAdd(out, (float)(mean / (double)BATCH));
    }
}

extern "C" void kernel_launch(void* const* d_in, const int* in_sizes, int n_in,
                              void* d_out, int out_size, void* d_ws, size_t ws_size,
                              hipStream_t stream) {
    const float* outp = (const float*)d_in[0];
    const float* labp = (const float*)d_in[1];
    unsigned long long* ghist = (unsigned long long*)d_ws;
    float* out = (float*)d_out;

    hipMemsetAsync(d_ws, 0, WS_ZERO_BYTES, stream);
    hipMemsetAsync(d_out, 0, sizeof(float), stream);

    histsum_kernel<<<dim3(BPS, BATCH), THREADS, 0, stream>>>(outp, labp, ghist);
    select_final_kernel<<<BATCH, THREADS, 0, stream>>>(ghist, out);
}